// Round 1
// baseline (324.033 us; speedup 1.0000x reference)
//
#include <hip/hip_runtime.h>

#define HID 2048
#define INTER 5632
#define KVW 256
#define NL 6
#define RMS_EPS 1e-6f

// ---------------- wave helpers (wave64) ----------------
__device__ __forceinline__ float waveAllSum(float v) {
#pragma unroll
    for (int m = 32; m > 0; m >>= 1) v += __shfl_xor(v, m, 64);
    return v;
}
__device__ __forceinline__ float waveAllMax(float v) {
#pragma unroll
    for (int m = 32; m > 0; m >>= 1) v = fmaxf(v, __shfl_xor(v, m, 64));
    return v;
}

__device__ __forceinline__ float dot4(float4 a, float4 b, float acc) {
    acc = fmaf(a.x, b.x, acc);
    acc = fmaf(a.y, b.y, acc);
    acc = fmaf(a.z, b.z, acc);
    acc = fmaf(a.w, b.w, acc);
    return acc;
}

// Load h (2048 fp32), compute rms factor (block-redundant), write normalized
// x = h * f * nw into xs (LDS). 256 threads.
__device__ __forceinline__ void load_norm_x(const float* __restrict__ h,
                                            const float* __restrict__ nw,
                                            float* xs, float* sm) {
    const int tid = threadIdx.x;
    const float4* h4 = (const float4*)h;
    float4 a = h4[tid * 2];
    float4 b = h4[tid * 2 + 1];
    float ss = a.x * a.x + a.y * a.y + a.z * a.z + a.w * a.w +
               b.x * b.x + b.y * b.y + b.z * b.z + b.w * b.w;
    ss = waveAllSum(ss);
    const int lane = tid & 63, wid = tid >> 6;
    if (lane == 0) sm[wid] = ss;
    __syncthreads();
    const float tot = sm[0] + sm[1] + sm[2] + sm[3];
    const float f = rsqrtf(tot * (1.0f / (float)HID) + RMS_EPS);
    const float4* n4 = (const float4*)nw;
    float4 na = n4[tid * 2];
    float4 nb = n4[tid * 2 + 1];
    float4* xs4 = (float4*)xs;
    xs4[tid * 2]     = make_float4(a.x * f * na.x, a.y * f * na.y, a.z * f * na.z, a.w * f * na.w);
    xs4[tid * 2 + 1] = make_float4(b.x * f * nb.x, b.y * f * nb.y, b.z * f * nb.z, b.w * f * nb.w);
    __syncthreads();
}

// ---------------- kernels ----------------

__global__ __launch_bounds__(256) void k_init(const float* __restrict__ x,
                                              float* __restrict__ h) {
    int i = blockIdx.x * 256 + threadIdx.x;
    h[i] = x[i];
}

// out[row] = dot(W[row,:], rmsnorm(h, nw))     W: [2048,2048], grid 512x256
__global__ __launch_bounds__(256) void k_rms_matvec(const float* __restrict__ h,
                                                    const float* __restrict__ nw,
                                                    const float* __restrict__ Wm,
                                                    float* __restrict__ out) {
    __shared__ float xs[HID];
    __shared__ float sm[4];
    load_norm_x(h, nw, xs, sm);
    const int lane = threadIdx.x & 63, wid = threadIdx.x >> 6;
    const int row = blockIdx.x * 4 + wid;
    const float4* Wr = (const float4*)(Wm + (size_t)row * HID);
    const float4* X4 = (const float4*)xs;
    float acc = 0.f;
#pragma unroll
    for (int k = 0; k < 8; ++k) {
        acc = dot4(Wr[k * 64 + lane], X4[k * 64 + lane], acc);
    }
    acc = waveAllSum(acc);
    if (lane == 0) out[row] = acc;
}

// partial[b][j] = sum_{i in chunk b} q[i]*kvw[i*256+j]   grid 32x256
__global__ __launch_bounds__(256) void k_scores(const float* __restrict__ q,
                                                const float* __restrict__ kvw,
                                                float* __restrict__ partial) {
    const int j = threadIdx.x;
    const int i0 = blockIdx.x * 64;
    float acc = 0.f;
#pragma unroll 8
    for (int i = i0; i < i0 + 64; ++i) {
        acc = fmaf(q[i], kvw[(size_t)i * KVW + j], acc);
    }
    partial[blockIdx.x * KVW + j] = acc;
}

// reduce partials -> softmax (block-redundant) -> ctx rows.  grid 32x256
__global__ __launch_bounds__(256) void k_ctx(const float* __restrict__ partial,
                                             const float* __restrict__ kvw,
                                             float* __restrict__ ctx) {
    __shared__ float p[KVW];
    __shared__ float sm[8];
    const int tid = threadIdx.x;
    float s = 0.f;
#pragma unroll 8
    for (int b = 0; b < 32; ++b) s += partial[b * KVW + tid];
    const int lane = tid & 63, wid = tid >> 6;
    float m = waveAllMax(s);
    if (lane == 0) sm[wid] = m;
    __syncthreads();
    m = fmaxf(fmaxf(sm[0], sm[1]), fmaxf(sm[2], sm[3]));
    float e = __expf(s - m);
    float t = waveAllSum(e);
    if (lane == 0) sm[4 + wid] = t;
    __syncthreads();
    const float denom = sm[4] + sm[5] + sm[6] + sm[7];
    p[tid] = e / denom;
    __syncthreads();
    // 64 rows per block, 16 per wave
#pragma unroll 4
    for (int r = 0; r < 16; ++r) {
        const int i = blockIdx.x * 64 + wid * 16 + r;
        const float4 k4 = ((const float4*)(kvw + (size_t)i * KVW))[lane];
        float acc = k4.x * p[lane * 4] + k4.y * p[lane * 4 + 1] +
                    k4.z * p[lane * 4 + 2] + k4.w * p[lane * 4 + 3];
        acc = waveAllSum(acc);
        if (lane == 0) ctx[i] = acc;
    }
}

// out[row] = h[row] + dot(W[row,:], v)   (in-place safe: each row touched once)
__global__ __launch_bounds__(256) void k_matvec_add(const float* __restrict__ h,
                                                    const float* __restrict__ Wm,
                                                    const float* __restrict__ v,
                                                    float* __restrict__ out) {
    __shared__ float xs[HID];
    const int tid = threadIdx.x;
    ((float4*)xs)[tid * 2]     = ((const float4*)v)[tid * 2];
    ((float4*)xs)[tid * 2 + 1] = ((const float4*)v)[tid * 2 + 1];
    __syncthreads();
    const int lane = tid & 63, wid = tid >> 6;
    const int row = blockIdx.x * 4 + wid;
    const float4* Wr = (const float4*)(Wm + (size_t)row * HID);
    const float4* X4 = (const float4*)xs;
    float acc = 0.f;
#pragma unroll
    for (int k = 0; k < 8; ++k) {
        acc = dot4(Wr[k * 64 + lane], X4[k * 64 + lane], acc);
    }
    acc = waveAllSum(acc);
    if (lane == 0) out[row] = h[row] + acc;
}

// inter[j] = silu(Wg[j,:]@x2) * (Wu[j,:]@x2), x2 = rmsnorm(h,n2w)  grid 1408x256
__global__ __launch_bounds__(256) void k_gateup(const float* __restrict__ h,
                                                const float* __restrict__ n2w,
                                                const float* __restrict__ Wg,
                                                const float* __restrict__ Wu,
                                                float* __restrict__ inter) {
    __shared__ float xs[HID];
    __shared__ float sm[4];
    load_norm_x(h, n2w, xs, sm);
    const int lane = threadIdx.x & 63, wid = threadIdx.x >> 6;
    const int j = blockIdx.x * 4 + wid;
    const float4* Gr = (const float4*)(Wg + (size_t)j * HID);
    const float4* Ur = (const float4*)(Wu + (size_t)j * HID);
    const float4* X4 = (const float4*)xs;
    float ag = 0.f, au = 0.f;
#pragma unroll
    for (int k = 0; k < 8; ++k) {
        const float4 x = X4[k * 64 + lane];
        ag = dot4(Gr[k * 64 + lane], x, ag);
        au = dot4(Ur[k * 64 + lane], x, au);
    }
    ag = waveAllSum(ag);
    au = waveAllSum(au);
    if (lane == 0) {
        const float sg = ag / (1.0f + __expf(-ag));  // silu
        inter[j] = sg * au;
    }
}

// out[row] = h[row] + sigmoid(Wshg@x2) * dot(Wd[row,:], inter)   grid 512x256
__global__ __launch_bounds__(256) void k_down(const float* __restrict__ h,
                                              const float* __restrict__ n2w,
                                              const float* __restrict__ Wshg,
                                              const float* __restrict__ Wd,
                                              const float* __restrict__ inter,
                                              float* __restrict__ out) {
    __shared__ float xs[INTER];
    __shared__ float sm[8];
    const int tid = threadIdx.x;
    const int lane = tid & 63, wid = tid >> 6;
    // ssq(h) and Wshg . (h*nw) combined (factor applied after)
    {
        const float4* h4 = (const float4*)h;
        const float4* w4 = (const float4*)Wshg;
        const float4* n4 = (const float4*)n2w;
        float4 a = h4[tid * 2], b = h4[tid * 2 + 1];
        float4 wa = w4[tid * 2], wb = w4[tid * 2 + 1];
        float4 na = n4[tid * 2], nb = n4[tid * 2 + 1];
        float ss = a.x * a.x + a.y * a.y + a.z * a.z + a.w * a.w +
                   b.x * b.x + b.y * b.y + b.z * b.z + b.w * b.w;
        float sg = a.x * wa.x * na.x + a.y * wa.y * na.y + a.z * wa.z * na.z + a.w * wa.w * na.w +
                   b.x * wb.x * nb.x + b.y * wb.y * nb.y + b.z * wb.z * nb.z + b.w * wb.w * nb.w;
        ss = waveAllSum(ss);
        sg = waveAllSum(sg);
        if (lane == 0) { sm[wid] = ss; sm[4 + wid] = sg; }
    }
    __syncthreads();
    const float tot = sm[0] + sm[1] + sm[2] + sm[3];
    const float f = rsqrtf(tot * (1.0f / (float)HID) + RMS_EPS);
    float gl = (sm[4] + sm[5] + sm[6] + sm[7]) * f;
    const float g = 1.0f / (1.0f + __expf(-gl));
    // stage inter[5632] into LDS: 11 float2 per thread
    {
        float2* xs2 = (float2*)xs;
        const float2* in2 = (const float2*)inter;
#pragma unroll
        for (int k = 0; k < 11; ++k) xs2[k * 256 + tid] = in2[k * 256 + tid];
    }
    __syncthreads();
    const int row = blockIdx.x * 4 + wid;
    const float4* Dr = (const float4*)(Wd + (size_t)row * INTER);
    const float4* X4 = (const float4*)xs;
    float acc = 0.f;
#pragma unroll
    for (int k = 0; k < 22; ++k) {
        acc = dot4(Dr[k * 64 + lane], X4[k * 64 + lane], acc);
    }
    acc = waveAllSum(acc);
    if (lane == 0) out[row] = h[row] + g * acc;
}

// ---------------- host ----------------
extern "C" void kernel_launch(void* const* d_in, const int* in_sizes, int n_in,
                              void* d_out, int out_size, void* d_ws, size_t ws_size,
                              hipStream_t stream) {
    const float* x     = (const float*)d_in[0];
    const float* kvw   = (const float*)d_in[1];
    const float* n1w   = (const float*)d_in[2];   // [6,2048]
    const float* n2w   = (const float*)d_in[3];   // [6,2048]
    const float* q_w   = (const float*)d_in[4];   // [6,2048,2048]
    // d_in[5]=k_w, d_in[6]=v_w: dead in reference, skipped
    const float* o_w   = (const float*)d_in[7];   // [6,2048,2048]
    // d_in[8]=router_w: dead
    const float* shg_w = (const float*)d_in[9];   // [6,1,2048]
    const float* g_w   = (const float*)d_in[10];  // [6,5632,2048]
    const float* u_w   = (const float*)d_in[11];  // [6,5632,2048]
    const float* dn_w  = (const float*)d_in[12];  // [6,2048,5632]
    float* out = (float*)d_out;

    float* ws = (float*)d_ws;
    float* hA      = ws;                 // 2048
    float* hB      = ws + 2048;          // 2048
    float* qv      = ws + 4096;          // 2048
    float* ctx     = ws + 6144;          // 2048
    float* partial = ws + 8192;          // 32*256 = 8192
    float* inter   = ws + 16384;         // 5632

    k_init<<<HID / 256, 256, 0, stream>>>(x, hA);

    float* hcur = hA;
    float* hnext = hB;
    for (int L = 0; L < NL; ++L) {
        const size_t o2 = (size_t)L * HID * HID;
        const size_t oi = (size_t)L * INTER * HID;
        k_rms_matvec<<<HID / 4, 256, 0, stream>>>(hcur, n1w + L * HID, q_w + o2, qv);
        k_scores<<<32, 256, 0, stream>>>(qv, kvw, partial);
        k_ctx<<<32, 256, 0, stream>>>(partial, kvw, ctx);
        k_matvec_add<<<HID / 4, 256, 0, stream>>>(hcur, o_w + o2, ctx, hcur);
        k_gateup<<<INTER / 4, 256, 0, stream>>>(hcur, n2w + L * HID, g_w + oi, u_w + oi, inter);
        float* dst = (L == NL - 1) ? out : hnext;
        k_down<<<HID / 4, 256, 0, stream>>>(hcur, n2w + L * HID, shg_w + L * HID,
                                            dn_w + oi, inter, dst);
        float* t = hcur; hcur = hnext; hnext = t;
    }
}